// Round 7
// baseline (388.977 us; speedup 1.0000x reference)
//
#include <hip/hip_runtime.h>
#include <math.h>

#define N_NODES 50000
#define N_GRAPHS 64
#define HID 128
#define SCAN_B 196  // ceil(50000/256)

typedef _Float16 half8 __attribute__((ext_vector_type(8)));
typedef float f32x4 __attribute__((ext_vector_type(4)));

__device__ __forceinline__ float lrelu(float e) { return e > 0.f ? e : 0.2f * e; }

// ---------------- CSR build ----------------
__global__ void count_kernel(const int* __restrict__ dst, int n_e, int* __restrict__ counts) {
    int e = blockIdx.x * blockDim.x + threadIdx.x;
    if (e < n_e) atomicAdd(&counts[dst[e]], 1);
}

// also initializes graph-boundary sentinel array (folded launch)
__global__ __launch_bounds__(256) void block_reduce(const int* __restrict__ counts,
                                                    int* __restrict__ bsum,
                                                    int* __restrict__ start) {
    __shared__ int red[256];
    int t = threadIdx.x;
    if (blockIdx.x == 0 && t <= N_GRAPHS) start[t] = N_NODES;
    int i = blockIdx.x * 256 + t;
    red[t] = (i < N_NODES) ? counts[i] : 0;
    __syncthreads();
#pragma unroll
    for (int off = 128; off; off >>= 1) {
        if (t < off) red[t] += red[t + off];
        __syncthreads();
    }
    if (t == 0) bsum[blockIdx.x] = red[0];
}

__global__ __launch_bounds__(256) void scan_bsum(const int* __restrict__ bsum,
                                                 int* __restrict__ bpre,
                                                 int* __restrict__ offs) {
    __shared__ int sh[256];
    int t = threadIdx.x;
    int v = (t < SCAN_B) ? bsum[t] : 0;
    sh[t] = v;
    __syncthreads();
#pragma unroll
    for (int off = 1; off < 256; off <<= 1) {
        int u = (t >= off) ? sh[t - off] : 0;
        __syncthreads();
        sh[t] += u;
        __syncthreads();
    }
    if (t < SCAN_B) bpre[t] = sh[t] - v;
    if (t == SCAN_B - 1) offs[N_NODES] = sh[t];
}

__global__ __launch_bounds__(256) void block_scan(const int* __restrict__ counts,
                                                  const int* __restrict__ bpre,
                                                  int* __restrict__ offs,
                                                  int* __restrict__ cursor) {
    __shared__ int sh[256];
    int t = threadIdx.x;
    int i = blockIdx.x * 256 + t;
    int c = (i < N_NODES) ? counts[i] : 0;
    sh[t] = c;
    __syncthreads();
#pragma unroll
    for (int off = 1; off < 256; off <<= 1) {
        int u = (t >= off) ? sh[t - off] : 0;
        __syncthreads();
        sh[t] += u;
        __syncthreads();
    }
    if (i < N_NODES) {
        int e = bpre[blockIdx.x] + sh[t] - c;
        offs[i] = e;
        cursor[i] = e;
    }
}

__global__ void scatter_kernel(const int* __restrict__ src, const int* __restrict__ dst, int n_e,
                               int* __restrict__ cursor, int* __restrict__ csr_src) {
    int e = blockIdx.x * blockDim.x + threadIdx.x;
    if (e >= n_e) return;
    int d = dst[e];
    int pos = atomicAdd(&cursor[d], 1);
    csr_src[pos] = src[e];
}

// ---------------- graph boundary detection ----------------
__global__ void find_start(const int* __restrict__ batch, int* __restrict__ start) {
    int i = blockIdx.x * blockDim.x + threadIdx.x;
    if (i >= N_NODES) return;
    int b = batch[i];
    if (i == 0) {
        start[b] = 0;
    } else {
        int pb = batch[i - 1];
        if (pb != b) start[b] = i;
    }
}

__global__ void fix_start(int* __restrict__ start) {
    if (threadIdx.x == 0) {
        for (int g = N_GRAPHS - 1; g >= 0; --g)
            if (start[g] == N_NODES) start[g] = start[g + 1];
    }
}

// ---------------- alpha weight folding: ws = W @ a_src, wd = W @ a_dst ----------------
// AS = (x@W)@a_src = x@(W@a_src): exact fp32 alphas, independent of MFMA precision.
__global__ __launch_bounds__(128) void prep_alpha(const float* __restrict__ W0,
                                                  const float* __restrict__ W1,
                                                  const float* __restrict__ W2,
                                                  const float* __restrict__ as0,
                                                  const float* __restrict__ ad0,
                                                  const float* __restrict__ as1,
                                                  const float* __restrict__ ad1,
                                                  const float* __restrict__ as2,
                                                  const float* __restrict__ ad2,
                                                  float* __restrict__ wfold) {
    // blockIdx: layer*2 + (0=src,1=dst); wfold[layer][which][128]
    int layer = blockIdx.x >> 1, which = blockIdx.x & 1;
    const float* W = layer == 0 ? W0 : (layer == 1 ? W1 : W2);
    const float* a = which == 0 ? (layer == 0 ? as0 : (layer == 1 ? as1 : as2))
                                : (layer == 0 ? ad0 : (layer == 1 ? ad1 : ad2));
    int k = threadIdx.x;
    float s = 0.f;
    for (int j = 0; j < 128; ++j) s = fmaf(W[k * 128 + j], a[j], s);
    wfold[(layer * 2 + which) * 128 + k] = s;
}

// ---------------- W fragment packing (split-f16, B-operand layout) ----------------
__global__ void pack_w3(const float* __restrict__ W0, const float* __restrict__ W1,
                        const float* __restrict__ W2,
                        _Float16* __restrict__ Wh0, _Float16* __restrict__ Wl0,
                        _Float16* __restrict__ Wh1, _Float16* __restrict__ Wl1,
                        _Float16* __restrict__ Wh2, _Float16* __restrict__ Wl2) {
    int layer = blockIdx.x >> 3;
    const float* W = layer == 0 ? W0 : (layer == 1 ? W1 : W2);
    _Float16* Wh = layer == 0 ? Wh0 : (layer == 1 ? Wh1 : Wh2);
    _Float16* Wl = layer == 0 ? Wl0 : (layer == 1 ? Wl1 : Wl2);
    int t = (blockIdx.x & 7) * 256 + threadIdx.x;
    int lane = t & 63;
    int nt = (t >> 6) & 7;
    int kt = t >> 9;
    int n = nt * 16 + (lane & 15);
    int kbase = kt * 32 + (lane >> 4) * 8;
#pragma unroll
    for (int j = 0; j < 8; ++j) {
        float w = W[(size_t)(kbase + j) * 128 + n];
        _Float16 h = (_Float16)w;
        float r = w - (float)h;
        size_t idx = (size_t)t * 8 + j;
        Wh[idx] = h;
        Wl[idx] = (_Float16)r;
    }
}

// ---------------- MFMA GEMM: H16 = fp16(X)@W (2-term); exact fp32 alphas in-loop ----------------
__global__ __launch_bounds__(256) void gemm_mfma(const float* __restrict__ X,
                                                 const _Float16* __restrict__ Wh,
                                                 const _Float16* __restrict__ Wl,
                                                 const float* __restrict__ wsv,
                                                 const float* __restrict__ wdv,
                                                 _Float16* __restrict__ H16,
                                                 float* __restrict__ AS,
                                                 float* __restrict__ AD) {
    __shared__ float wsL[128], wdL[128];
    int t = threadIdx.x;
    if (t < 128) wsL[t] = wsv[t];
    else if (t < 256) wdL[t - 128] = wdv[t - 128];
    __syncthreads();

    int wave = t >> 6, lane = t & 63;
    int m15 = lane & 15, quad = lane >> 4;
    int rowbase = blockIdx.x * 64 + wave * 16;
    int arow = rowbase + m15;
    bool arow_ok = arow < N_NODES;

    f32x4 acc[8];
#pragma unroll
    for (int nt = 0; nt < 8; ++nt) acc[nt] = (f32x4){0.f, 0.f, 0.f, 0.f};
    float as_p = 0.f, ad_p = 0.f;  // fp32 alpha partials over this lane's k-slice

    const float* xrow = X + (size_t)arow * 128 + quad * 8;
#pragma unroll
    for (int kt = 0; kt < 4; ++kt) {
        f32x4 a0 = (f32x4){0.f, 0.f, 0.f, 0.f};
        f32x4 a1 = (f32x4){0.f, 0.f, 0.f, 0.f};
        if (arow_ok) {
            a0 = *(const f32x4*)(xrow + kt * 32);
            a1 = *(const f32x4*)(xrow + kt * 32 + 4);
        }
        int kb = kt * 32 + quad * 8;
        half8 ah;
#pragma unroll
        for (int j = 0; j < 4; ++j) {
            as_p = fmaf(a0[j], wsL[kb + j], as_p);
            ad_p = fmaf(a0[j], wdL[kb + j], ad_p);
            as_p = fmaf(a1[j], wsL[kb + 4 + j], as_p);
            ad_p = fmaf(a1[j], wdL[kb + 4 + j], ad_p);
            ah[j] = (_Float16)a0[j];
            ah[4 + j] = (_Float16)a1[j];
        }
#pragma unroll
        for (int nt = 0; nt < 8; ++nt) {
            size_t fidx = ((size_t)((kt * 8 + nt) * 64 + lane)) * 8;
            half8 bh = *(const half8*)(Wh + fidx);
            half8 bl = *(const half8*)(Wl + fidx);
            acc[nt] = __builtin_amdgcn_mfma_f32_16x16x32_f16(ah, bh, acc[nt], 0, 0, 0);
            acc[nt] = __builtin_amdgcn_mfma_f32_16x16x32_f16(ah, bl, acc[nt], 0, 0, 0);
        }
    }

    // H16 store: C/D layout col = nt*16 + m15, row = quad*4 + reg
#pragma unroll
    for (int nt = 0; nt < 8; ++nt) {
        int c = nt * 16 + m15;
#pragma unroll
        for (int reg = 0; reg < 4; ++reg) {
            int gr = rowbase + quad * 4 + reg;
            if (gr < N_NODES) H16[(size_t)gr * 128 + c] = (_Float16)acc[nt][reg];
        }
    }
    // alpha reduce across quads (lanes m15, m15+16, m15+32, m15+48 hold row arow)
    as_p += __shfl_xor(as_p, 16);
    ad_p += __shfl_xor(ad_p, 16);
    as_p += __shfl_xor(as_p, 32);
    ad_p += __shfl_xor(ad_p, 32);
    if (quad == 0 && arow_ok) { AS[arow] = as_p; AD[arow] = ad_p; }
}

// ---------------- softmax coefs: one wave per node (normalized, inv folded in) ----------------
__global__ __launch_bounds__(256) void coef_kernel(const float* __restrict__ AS,
                                                   const float* __restrict__ AD,
                                                   const int* __restrict__ offs,
                                                   const int* __restrict__ csr_src,
                                                   float* __restrict__ pcoef,
                                                   float* __restrict__ pself) {
    int node = blockIdx.x * 4 + (threadIdx.x >> 6);
    if (node >= N_NODES) return;
    int lane = threadIdx.x & 63;
    int beg = offs[node], end = offs[node + 1];
    int deg = end - beg;
    float ad = AD[node];
    float eself = lrelu(AS[node] + ad);

    if (deg <= 64) {
        float ev = -INFINITY;
        if (lane < deg) ev = lrelu(AS[csr_src[beg + lane]] + ad);
        float m = ev;
#pragma unroll
        for (int off = 32; off; off >>= 1) m = fmaxf(m, __shfl_xor(m, off));
        m = fmaxf(m, eself);
        float p = (lane < deg) ? expf(ev - m) : 0.f;
        float ssum = p;
#pragma unroll
        for (int off = 32; off; off >>= 1) ssum += __shfl_xor(ssum, off);
        float ps = expf(eself - m);
        float inv = 1.f / (ssum + ps + 1e-16f);
        if (lane < deg) pcoef[beg + lane] = p * inv;
        if (lane == 0) pself[node] = ps * inv;
    } else {
        float mym = -INFINITY;
        for (int i = beg + lane; i < end; i += 64)
            mym = fmaxf(mym, lrelu(AS[csr_src[i]] + ad));
#pragma unroll
        for (int off = 32; off; off >>= 1) mym = fmaxf(mym, __shfl_xor(mym, off));
        float m = fmaxf(mym, eself);
        float ssum = 0.f;
        for (int i = beg + lane; i < end; i += 64)
            ssum += expf(lrelu(AS[csr_src[i]] + ad) - m);
#pragma unroll
        for (int off = 32; off; off >>= 1) ssum += __shfl_xor(ssum, off);
        float ps = expf(eself - m);
        float inv = 1.f / (ssum + ps + 1e-16f);
        for (int i = beg + lane; i < end; i += 64)
            pcoef[i] = expf(lrelu(AS[csr_src[i]] + ad) - m) * inv;
        if (lane == 0) pself[node] = ps * inv;
    }
}

// ---------------- fp16 gather: one wave per node, quarter-wave rows (16 x 16B) ----------------
// 4 edges in flight per wave + 2-way unroll per quarter = 8 outstanding row loads.
__global__ __launch_bounds__(256) void gather_kernel(const _Float16* __restrict__ H16,
                                                     const float* __restrict__ pcoef,
                                                     const float* __restrict__ pself,
                                                     const int* __restrict__ offs,
                                                     const int* __restrict__ csr_src,
                                                     const float* __restrict__ bias,
                                                     float* __restrict__ OUT) {
    int node = blockIdx.x * 4 + (threadIdx.x >> 6);
    if (node >= N_NODES) return;
    int lane = threadIdx.x & 63;
    int q = lane >> 4, l16 = lane & 15;
    int beg = offs[node], end = offs[node + 1];
    const half8* H8 = (const half8*)H16;  // row = 16 half8

    float accA[8] = {0.f, 0.f, 0.f, 0.f, 0.f, 0.f, 0.f, 0.f};
    float accB[8] = {0.f, 0.f, 0.f, 0.f, 0.f, 0.f, 0.f, 0.f};

    int e = beg + q;
    for (; e + 4 < end; e += 8) {
        int s0 = csr_src[e];
        int s1 = csr_src[e + 4];
        float c0 = pcoef[e];
        float c1 = pcoef[e + 4];
        half8 h0 = H8[(size_t)s0 * 16 + l16];
        half8 h1 = H8[(size_t)s1 * 16 + l16];
#pragma unroll
        for (int i = 0; i < 8; ++i) {
            accA[i] = fmaf(c0, (float)h0[i], accA[i]);
            accB[i] = fmaf(c1, (float)h1[i], accB[i]);
        }
    }
    if (e < end) {
        int s0 = csr_src[e];
        float c0 = pcoef[e];
        half8 h0 = H8[(size_t)s0 * 16 + l16];
#pragma unroll
        for (int i = 0; i < 8; ++i) accA[i] = fmaf(c0, (float)h0[i], accA[i]);
    }

#pragma unroll
    for (int i = 0; i < 8; ++i) {
        accA[i] += accB[i];
        accA[i] += __shfl_xor(accA[i], 16);
        accA[i] += __shfl_xor(accA[i], 32);
    }

    if (q == 0) {
        float ps = pself[node];
        half8 hs = H8[(size_t)node * 16 + l16];
        f32x4 b4a = ((const f32x4*)bias)[l16 * 2];
        f32x4 b4b = ((const f32x4*)bias)[l16 * 2 + 1];
        f32x4 o0, o1;
        o0.x = fmaf(ps, (float)hs[0], accA[0]) + b4a.x;
        o0.y = fmaf(ps, (float)hs[1], accA[1]) + b4a.y;
        o0.z = fmaf(ps, (float)hs[2], accA[2]) + b4a.z;
        o0.w = fmaf(ps, (float)hs[3], accA[3]) + b4a.w;
        o1.x = fmaf(ps, (float)hs[4], accA[4]) + b4b.x;
        o1.y = fmaf(ps, (float)hs[5], accA[5]) + b4b.y;
        o1.z = fmaf(ps, (float)hs[6], accA[6]) + b4b.z;
        o1.w = fmaf(ps, (float)hs[7], accA[7]) + b4b.w;
        o0.x = o0.x > 0.f ? o0.x : expm1f(o0.x);
        o0.y = o0.y > 0.f ? o0.y : expm1f(o0.y);
        o0.z = o0.z > 0.f ? o0.z : expm1f(o0.z);
        o0.w = o0.w > 0.f ? o0.w : expm1f(o0.w);
        o1.x = o1.x > 0.f ? o1.x : expm1f(o1.x);
        o1.y = o1.y > 0.f ? o1.y : expm1f(o1.y);
        o1.z = o1.z > 0.f ? o1.z : expm1f(o1.z);
        o1.w = o1.w > 0.f ? o1.w : expm1f(o1.w);
        ((f32x4*)OUT)[(size_t)node * 32 + l16 * 2] = o0;
        ((f32x4*)OUT)[(size_t)node * 32 + l16 * 2 + 1] = o1;
    }
}

// ---------------- global mean pool: 2-phase ----------------
__global__ __launch_bounds__(128) void pool_partial(const float* __restrict__ F,
                                                    const int* __restrict__ start,
                                                    float* __restrict__ partial) {
    int b = blockIdx.x;
    int g = b >> 4, sub = b & 15;
    int c = threadIdx.x;
    int s0 = start[g], e0 = start[g + 1];
    float acc = 0.f;
    for (int i = s0 + sub; i < e0; i += 16) acc += F[(size_t)i * 128 + c];
    partial[(size_t)b * 128 + c] = acc;
}

__global__ __launch_bounds__(128) void pool_final(const float* __restrict__ partial,
                                                  const int* __restrict__ start,
                                                  float* __restrict__ out) {
    int g = blockIdx.x;
    int c = threadIdx.x;
    float v = 0.f;
#pragma unroll
    for (int u = 0; u < 16; ++u) v += partial[(size_t)(g * 16 + u) * 128 + c];
    int cnt = start[g + 1] - start[g];
    out[(size_t)g * 128 + c] = v / (float)(cnt > 1 ? cnt : 1);
}

extern "C" void kernel_launch(void* const* d_in, const int* in_sizes, int n_in,
                              void* d_out, int out_size, void* d_ws, size_t ws_size,
                              hipStream_t stream) {
    const float* x = (const float*)d_in[0];
    const int* edge_index = (const int*)d_in[1];
    const int* batch = (const int*)d_in[2];
    const float* W[3]   = {(const float*)d_in[3], (const float*)d_in[7], (const float*)d_in[11]};
    const float* avs[3] = {(const float*)d_in[4], (const float*)d_in[8], (const float*)d_in[12]};
    const float* avd[3] = {(const float*)d_in[5], (const float*)d_in[9], (const float*)d_in[13]};
    const float* bb[3]  = {(const float*)d_in[6], (const float*)d_in[10], (const float*)d_in[14]};
    int E0 = in_sizes[1] / 2;
    const int* esrc = edge_index;
    const int* edst = edge_index + E0;

    char* p = (char*)d_ws;
    auto alloc = [&](size_t bytes) -> void* {
        void* q = (void*)p;
        p += (bytes + 255) & ~(size_t)255;
        return q;
    };
    int* counts   = (int*)alloc((size_t)N_NODES * 4);
    int* offs     = (int*)alloc((size_t)(N_NODES + 1) * 4);
    int* cursor   = (int*)alloc((size_t)N_NODES * 4);
    int* csr_src  = (int*)alloc((size_t)E0 * 4);
    int* start    = (int*)alloc((N_GRAPHS + 1) * 4);
    int* bsum     = (int*)alloc(SCAN_B * 4);
    int* bpre     = (int*)alloc(SCAN_B * 4);
    float* AS     = (float*)alloc((size_t)N_NODES * 4);
    float* AD     = (float*)alloc((size_t)N_NODES * 4);
    float* pcoef  = (float*)alloc((size_t)E0 * 4);
    float* pself  = (float*)alloc((size_t)N_NODES * 4);
    float* wfold  = (float*)alloc(6 * 128 * 4);
    _Float16* H16 = (_Float16*)alloc((size_t)N_NODES * HID * 2);
    float* FA     = (float*)alloc((size_t)N_NODES * HID * 4);
    float* FB     = (float*)alloc((size_t)N_NODES * HID * 4);
    float* partial = (float*)alloc((size_t)N_GRAPHS * 16 * 128 * 4);
    _Float16* Wh[3], *Wl[3];
    for (int l = 0; l < 3; ++l) {
        Wh[l] = (_Float16*)alloc(16384 * 2);
        Wl[l] = (_Float16*)alloc(16384 * 2);
    }

    // CSR build
    hipMemsetAsync(counts, 0, (size_t)N_NODES * 4, stream);
    count_kernel<<<(E0 + 255) / 256, 256, 0, stream>>>(edst, E0, counts);
    block_reduce<<<SCAN_B, 256, 0, stream>>>(counts, bsum, start);
    scan_bsum<<<1, 256, 0, stream>>>(bsum, bpre, offs);
    block_scan<<<SCAN_B, 256, 0, stream>>>(counts, bpre, offs, cursor);
    scatter_kernel<<<(E0 + 255) / 256, 256, 0, stream>>>(esrc, edst, E0, cursor, csr_src);

    // graph boundaries (start[] sentinel init happened in block_reduce)
    find_start<<<(N_NODES + 255) / 256, 256, 0, stream>>>(batch, start);
    fix_start<<<1, 64, 0, stream>>>(start);

    // weight prep
    prep_alpha<<<6, 128, 0, stream>>>(W[0], W[1], W[2], avs[0], avd[0], avs[1], avd[1],
                                      avs[2], avd[2], wfold);
    pack_w3<<<24, 256, 0, stream>>>(W[0], W[1], W[2], Wh[0], Wl[0], Wh[1], Wl[1], Wh[2], Wl[2]);

    // 3 GAT layers
    const float* cur = x;
    float* feat[2] = {FA, FB};
    for (int l = 0; l < 3; ++l) {
        gemm_mfma<<<(N_NODES + 63) / 64, 256, 0, stream>>>(cur, Wh[l], Wl[l],
                                                           wfold + (l * 2) * 128,
                                                           wfold + (l * 2 + 1) * 128,
                                                           H16, AS, AD);
        coef_kernel<<<(N_NODES + 3) / 4, 256, 0, stream>>>(AS, AD, offs, csr_src, pcoef, pself);
        float* nxt = feat[l & 1];
        gather_kernel<<<(N_NODES + 3) / 4, 256, 0, stream>>>(H16, pcoef, pself, offs, csr_src,
                                                             bb[l], nxt);
        cur = nxt;
    }

    // global mean pool (2-phase)
    pool_partial<<<N_GRAPHS * 16, 128, 0, stream>>>(cur, start, partial);
    pool_final<<<N_GRAPHS, 128, 0, stream>>>(partial, start, (float*)d_out);
}

// Round 8
// 358.166 us; speedup vs baseline: 1.0860x; 1.0860x over previous
//
#include <hip/hip_runtime.h>
#include <math.h>

#define N_NODES 50000
#define N_GRAPHS 64
#define HID 128
#define SCAN_B 196  // ceil(50000/256)

typedef _Float16 half8 __attribute__((ext_vector_type(8)));
typedef float f32x4 __attribute__((ext_vector_type(4)));

__device__ __forceinline__ float lrelu(float e) { return e > 0.f ? e : 0.2f * e; }

// ---------------- CSR build ----------------
// also plants graph-boundary sentinels (-1) so find/fix kernels can be folded away
__global__ void count_kernel(const int* __restrict__ dst, int n_e, int* __restrict__ counts,
                             int* __restrict__ start) {
    if (blockIdx.x == 0 && threadIdx.x <= N_GRAPHS) start[threadIdx.x] = -1;
    int e = blockIdx.x * blockDim.x + threadIdx.x;
    if (e < n_e) atomicAdd(&counts[dst[e]], 1);
}

__global__ __launch_bounds__(256) void block_reduce(const int* __restrict__ counts,
                                                    int* __restrict__ bsum) {
    __shared__ int red[256];
    int t = threadIdx.x;
    int i = blockIdx.x * 256 + t;
    red[t] = (i < N_NODES) ? counts[i] : 0;
    __syncthreads();
#pragma unroll
    for (int off = 128; off; off >>= 1) {
        if (t < off) red[t] += red[t + off];
        __syncthreads();
    }
    if (t == 0) bsum[blockIdx.x] = red[0];
}

__global__ __launch_bounds__(256) void scan_bsum(const int* __restrict__ bsum,
                                                 int* __restrict__ bpre,
                                                 int* __restrict__ offs) {
    __shared__ int sh[256];
    int t = threadIdx.x;
    int v = (t < SCAN_B) ? bsum[t] : 0;
    sh[t] = v;
    __syncthreads();
#pragma unroll
    for (int off = 1; off < 256; off <<= 1) {
        int u = (t >= off) ? sh[t - off] : 0;
        __syncthreads();
        sh[t] += u;
        __syncthreads();
    }
    if (t < SCAN_B) bpre[t] = sh[t] - v;
    if (t == SCAN_B - 1) offs[N_NODES] = sh[t];
}

// + folded graph-boundary detection (same node index space; batch is sorted)
__global__ __launch_bounds__(256) void block_scan(const int* __restrict__ counts,
                                                  const int* __restrict__ bpre,
                                                  const int* __restrict__ batch,
                                                  int* __restrict__ offs,
                                                  int* __restrict__ cursor,
                                                  int* __restrict__ start) {
    __shared__ int sh[256];
    int t = threadIdx.x;
    int i = blockIdx.x * 256 + t;
    int c = (i < N_NODES) ? counts[i] : 0;
    sh[t] = c;
    __syncthreads();
#pragma unroll
    for (int off = 1; off < 256; off <<= 1) {
        int u = (t >= off) ? sh[t - off] : 0;
        __syncthreads();
        sh[t] += u;
        __syncthreads();
    }
    if (i < N_NODES) {
        int e = bpre[blockIdx.x] + sh[t] - c;
        offs[i] = e;
        cursor[i] = e;
        int b = batch[i];
        if (i == 0) start[b] = 0;
        else if (batch[i - 1] != b) start[b] = i;
    }
}

__global__ void scatter_kernel(const int* __restrict__ src, const int* __restrict__ dst, int n_e,
                               int* __restrict__ cursor, int* __restrict__ csr_src) {
    int e = blockIdx.x * blockDim.x + threadIdx.x;
    if (e >= n_e) return;
    int d = dst[e];
    int pos = atomicAdd(&cursor[d], 1);
    csr_src[pos] = src[e];
}

// ---------------- fused weight prep: split-f16 fragment pack + alpha fold ----------------
// blocks 0..23: pack; blocks 24..29: wfold[layer][which] = W @ a
__global__ __launch_bounds__(256) void pack_prep(const float* __restrict__ W0,
                                                 const float* __restrict__ W1,
                                                 const float* __restrict__ W2,
                                                 const float* __restrict__ as0,
                                                 const float* __restrict__ ad0,
                                                 const float* __restrict__ as1,
                                                 const float* __restrict__ ad1,
                                                 const float* __restrict__ as2,
                                                 const float* __restrict__ ad2,
                                                 _Float16* __restrict__ Wh0, _Float16* __restrict__ Wl0,
                                                 _Float16* __restrict__ Wh1, _Float16* __restrict__ Wl1,
                                                 _Float16* __restrict__ Wh2, _Float16* __restrict__ Wl2,
                                                 float* __restrict__ wfold) {
    int b = blockIdx.x;
    if (b < 24) {
        int layer = b >> 3;
        const float* W = layer == 0 ? W0 : (layer == 1 ? W1 : W2);
        _Float16* Wh = layer == 0 ? Wh0 : (layer == 1 ? Wh1 : Wh2);
        _Float16* Wl = layer == 0 ? Wl0 : (layer == 1 ? Wl1 : Wl2);
        int t = (b & 7) * 256 + threadIdx.x;
        int lane = t & 63;
        int nt = (t >> 6) & 7;
        int kt = t >> 9;
        int n = nt * 16 + (lane & 15);
        int kbase = kt * 32 + (lane >> 4) * 8;
#pragma unroll
        for (int j = 0; j < 8; ++j) {
            float w = W[(size_t)(kbase + j) * 128 + n];
            _Float16 h = (_Float16)w;
            float r = w - (float)h;
            size_t idx = (size_t)t * 8 + j;
            Wh[idx] = h;
            Wl[idx] = (_Float16)r;
        }
    } else {
        int idx = b - 24;  // 0..5: layer*2 + which
        int layer = idx >> 1, which = idx & 1;
        const float* W = layer == 0 ? W0 : (layer == 1 ? W1 : W2);
        const float* a = which == 0 ? (layer == 0 ? as0 : (layer == 1 ? as1 : as2))
                                    : (layer == 0 ? ad0 : (layer == 1 ? ad1 : ad2));
        int k = threadIdx.x;
        if (k < 128) {
            float s = 0.f;
            for (int j = 0; j < 128; ++j) s = fmaf(W[k * 128 + j], a[j], s);
            wfold[idx * 128 + k] = s;
        }
    }
}

// ---------------- MFMA GEMM: H16 = fp16(X)@W (2-term); exact fp32 alphas in-loop ----------------
__global__ __launch_bounds__(256) void gemm_mfma(const float* __restrict__ X,
                                                 const _Float16* __restrict__ Wh,
                                                 const _Float16* __restrict__ Wl,
                                                 const float* __restrict__ wsv,
                                                 const float* __restrict__ wdv,
                                                 _Float16* __restrict__ H16,
                                                 float* __restrict__ AS,
                                                 float* __restrict__ AD) {
    __shared__ float wsL[128], wdL[128];
    int t = threadIdx.x;
    if (t < 128) wsL[t] = wsv[t];
    else if (t < 256) wdL[t - 128] = wdv[t - 128];
    __syncthreads();

    int wave = t >> 6, lane = t & 63;
    int m15 = lane & 15, quad = lane >> 4;
    int rowbase = blockIdx.x * 64 + wave * 16;
    int arow = rowbase + m15;
    bool arow_ok = arow < N_NODES;

    f32x4 acc[8];
#pragma unroll
    for (int nt = 0; nt < 8; ++nt) acc[nt] = (f32x4){0.f, 0.f, 0.f, 0.f};
    float as_p = 0.f, ad_p = 0.f;

    const float* xrow = X + (size_t)arow * 128 + quad * 8;
#pragma unroll
    for (int kt = 0; kt < 4; ++kt) {
        f32x4 a0 = (f32x4){0.f, 0.f, 0.f, 0.f};
        f32x4 a1 = (f32x4){0.f, 0.f, 0.f, 0.f};
        if (arow_ok) {
            a0 = *(const f32x4*)(xrow + kt * 32);
            a1 = *(const f32x4*)(xrow + kt * 32 + 4);
        }
        int kb = kt * 32 + quad * 8;
        half8 ah;
#pragma unroll
        for (int j = 0; j < 4; ++j) {
            as_p = fmaf(a0[j], wsL[kb + j], as_p);
            ad_p = fmaf(a0[j], wdL[kb + j], ad_p);
            as_p = fmaf(a1[j], wsL[kb + 4 + j], as_p);
            ad_p = fmaf(a1[j], wdL[kb + 4 + j], ad_p);
            ah[j] = (_Float16)a0[j];
            ah[4 + j] = (_Float16)a1[j];
        }
#pragma unroll
        for (int nt = 0; nt < 8; ++nt) {
            size_t fidx = ((size_t)((kt * 8 + nt) * 64 + lane)) * 8;
            half8 bh = *(const half8*)(Wh + fidx);
            half8 bl = *(const half8*)(Wl + fidx);
            acc[nt] = __builtin_amdgcn_mfma_f32_16x16x32_f16(ah, bh, acc[nt], 0, 0, 0);
            acc[nt] = __builtin_amdgcn_mfma_f32_16x16x32_f16(ah, bl, acc[nt], 0, 0, 0);
        }
    }

#pragma unroll
    for (int nt = 0; nt < 8; ++nt) {
        int c = nt * 16 + m15;
#pragma unroll
        for (int reg = 0; reg < 4; ++reg) {
            int gr = rowbase + quad * 4 + reg;
            if (gr < N_NODES) H16[(size_t)gr * 128 + c] = (_Float16)acc[nt][reg];
        }
    }
    as_p += __shfl_xor(as_p, 16);
    ad_p += __shfl_xor(ad_p, 16);
    as_p += __shfl_xor(as_p, 32);
    ad_p += __shfl_xor(ad_p, 32);
    if (quad == 0 && arow_ok) { AS[arow] = as_p; AD[arow] = ad_p; }
}

// ---------------- fused softmax + fp16 gather: one wave per node ----------------
// Phase A: softmax coefs in registers -> s,p staged in LDS (2 KB/block).
// Phase B: quarter-wave row gather (16 lanes x 16B), 2-way unroll.
__global__ __launch_bounds__(256) void aggregate_kernel(const _Float16* __restrict__ H16,
                                                        const float* __restrict__ AS,
                                                        const float* __restrict__ AD,
                                                        const int* __restrict__ offs,
                                                        const int* __restrict__ csr_src,
                                                        const float* __restrict__ bias,
                                                        float* __restrict__ OUT) {
    __shared__ int sh_s[4][64];
    __shared__ float sh_p[4][64];
    int w = threadIdx.x >> 6, lane = threadIdx.x & 63;
    int node = blockIdx.x * 4 + w;
    bool valid = node < N_NODES;

    int beg = 0, deg = 0;
    float ad = 0.f, eself = 0.f;
    if (valid) {
        beg = offs[node];
        deg = offs[node + 1] - beg;
        ad = AD[node];
        eself = lrelu(AS[node] + ad);
    }
    bool fast = deg <= 64;
    float m = 0.f, inv = 1.f, ps = 0.f;

    if (valid) {
        if (fast) {
            int s = 0;
            float ev = -INFINITY;
            if (lane < deg) {
                s = csr_src[beg + lane];
                ev = lrelu(AS[s] + ad);
            }
            m = ev;
#pragma unroll
            for (int off = 32; off; off >>= 1) m = fmaxf(m, __shfl_xor(m, off));
            m = fmaxf(m, eself);
            float p = (lane < deg) ? expf(ev - m) : 0.f;
            float ssum = p;
#pragma unroll
            for (int off = 32; off; off >>= 1) ssum += __shfl_xor(ssum, off);
            ps = expf(eself - m);
            inv = 1.f / (ssum + ps + 1e-16f);
            ps *= inv;
            sh_s[w][lane] = s;
            sh_p[w][lane] = p * inv;
        } else {
            float mym = -INFINITY;
            for (int i = beg + lane; i < beg + deg; i += 64)
                mym = fmaxf(mym, lrelu(AS[csr_src[i]] + ad));
#pragma unroll
            for (int off = 32; off; off >>= 1) mym = fmaxf(mym, __shfl_xor(mym, off));
            m = fmaxf(mym, eself);
            float ssum = 0.f;
            for (int i = beg + lane; i < beg + deg; i += 64)
                ssum += expf(lrelu(AS[csr_src[i]] + ad) - m);
#pragma unroll
            for (int off = 32; off; off >>= 1) ssum += __shfl_xor(ssum, off);
            ps = expf(eself - m);
            inv = 1.f / (ssum + ps + 1e-16f);
            ps *= inv;
        }
    }
    __syncthreads();

    int q = lane >> 4, l16 = lane & 15;
    const half8* H8 = (const half8*)H16;  // row = 16 half8
    float accA[8] = {0.f, 0.f, 0.f, 0.f, 0.f, 0.f, 0.f, 0.f};
    float accB[8] = {0.f, 0.f, 0.f, 0.f, 0.f, 0.f, 0.f, 0.f};

    if (valid) {
        if (fast) {
            int k = q;
            for (; k + 4 < deg; k += 8) {
                int s0 = sh_s[w][k];
                int s1 = sh_s[w][k + 4];
                float c0 = sh_p[w][k];
                float c1 = sh_p[w][k + 4];
                half8 h0 = H8[(size_t)s0 * 16 + l16];
                half8 h1 = H8[(size_t)s1 * 16 + l16];
#pragma unroll
                for (int i = 0; i < 8; ++i) {
                    accA[i] = fmaf(c0, (float)h0[i], accA[i]);
                    accB[i] = fmaf(c1, (float)h1[i], accB[i]);
                }
            }
            if (k < deg) {
                int s0 = sh_s[w][k];
                float c0 = sh_p[w][k];
                half8 h0 = H8[(size_t)s0 * 16 + l16];
#pragma unroll
                for (int i = 0; i < 8; ++i) accA[i] = fmaf(c0, (float)h0[i], accA[i]);
            }
        } else {
            for (int k = q; k < deg; k += 4) {
                int s = csr_src[beg + k];
                float c = expf(lrelu(AS[s] + ad) - m) * inv;
                half8 h0 = H8[(size_t)s * 16 + l16];
#pragma unroll
                for (int i = 0; i < 8; ++i) accA[i] = fmaf(c, (float)h0[i], accA[i]);
            }
        }
    }

#pragma unroll
    for (int i = 0; i < 8; ++i) {
        accA[i] += accB[i];
        accA[i] += __shfl_xor(accA[i], 16);
        accA[i] += __shfl_xor(accA[i], 32);
    }

    if (valid && q == 0) {
        half8 hs = H8[(size_t)node * 16 + l16];
        f32x4 b4a = ((const f32x4*)bias)[l16 * 2];
        f32x4 b4b = ((const f32x4*)bias)[l16 * 2 + 1];
        f32x4 o0, o1;
        o0.x = fmaf(ps, (float)hs[0], accA[0]) + b4a.x;
        o0.y = fmaf(ps, (float)hs[1], accA[1]) + b4a.y;
        o0.z = fmaf(ps, (float)hs[2], accA[2]) + b4a.z;
        o0.w = fmaf(ps, (float)hs[3], accA[3]) + b4a.w;
        o1.x = fmaf(ps, (float)hs[4], accA[4]) + b4b.x;
        o1.y = fmaf(ps, (float)hs[5], accA[5]) + b4b.y;
        o1.z = fmaf(ps, (float)hs[6], accA[6]) + b4b.z;
        o1.w = fmaf(ps, (float)hs[7], accA[7]) + b4b.w;
        o0.x = o0.x > 0.f ? o0.x : expm1f(o0.x);
        o0.y = o0.y > 0.f ? o0.y : expm1f(o0.y);
        o0.z = o0.z > 0.f ? o0.z : expm1f(o0.z);
        o0.w = o0.w > 0.f ? o0.w : expm1f(o0.w);
        o1.x = o1.x > 0.f ? o1.x : expm1f(o1.x);
        o1.y = o1.y > 0.f ? o1.y : expm1f(o1.y);
        o1.z = o1.z > 0.f ? o1.z : expm1f(o1.z);
        o1.w = o1.w > 0.f ? o1.w : expm1f(o1.w);
        ((f32x4*)OUT)[(size_t)node * 32 + l16 * 2] = o0;
        ((f32x4*)OUT)[(size_t)node * 32 + l16 * 2 + 1] = o1;
    }
}

// ---------------- global mean pool: 2-phase, sentinel-walking boundaries ----------------
__device__ __forceinline__ int estart(const int* __restrict__ start, int g) {
    for (; g < N_GRAPHS; ++g) {
        int v = start[g];
        if (v >= 0) return v;
    }
    return N_NODES;
}

__global__ __launch_bounds__(128) void pool_partial(const float* __restrict__ F,
                                                    const int* __restrict__ start,
                                                    float* __restrict__ partial) {
    int b = blockIdx.x;
    int g = b >> 4, sub = b & 15;
    int c = threadIdx.x;
    int s0 = estart(start, g), e0 = estart(start, g + 1);
    float acc = 0.f;
    for (int i = s0 + sub; i < e0; i += 16) acc += F[(size_t)i * 128 + c];
    partial[(size_t)b * 128 + c] = acc;
}

__global__ __launch_bounds__(128) void pool_final(const float* __restrict__ partial,
                                                  const int* __restrict__ start,
                                                  float* __restrict__ out) {
    int g = blockIdx.x;
    int c = threadIdx.x;
    float v = 0.f;
#pragma unroll
    for (int u = 0; u < 16; ++u) v += partial[(size_t)(g * 16 + u) * 128 + c];
    int cnt = estart(start, g + 1) - estart(start, g);
    out[(size_t)g * 128 + c] = v / (float)(cnt > 1 ? cnt : 1);
}

extern "C" void kernel_launch(void* const* d_in, const int* in_sizes, int n_in,
                              void* d_out, int out_size, void* d_ws, size_t ws_size,
                              hipStream_t stream) {
    const float* x = (const float*)d_in[0];
    const int* edge_index = (const int*)d_in[1];
    const int* batch = (const int*)d_in[2];
    const float* W[3]   = {(const float*)d_in[3], (const float*)d_in[7], (const float*)d_in[11]};
    const float* avs[3] = {(const float*)d_in[4], (const float*)d_in[8], (const float*)d_in[12]};
    const float* avd[3] = {(const float*)d_in[5], (const float*)d_in[9], (const float*)d_in[13]};
    const float* bb[3]  = {(const float*)d_in[6], (const float*)d_in[10], (const float*)d_in[14]};
    int E0 = in_sizes[1] / 2;
    const int* esrc = edge_index;
    const int* edst = edge_index + E0;

    char* p = (char*)d_ws;
    auto alloc = [&](size_t bytes) -> void* {
        void* q = (void*)p;
        p += (bytes + 255) & ~(size_t)255;
        return q;
    };
    int* counts   = (int*)alloc((size_t)N_NODES * 4);
    int* offs     = (int*)alloc((size_t)(N_NODES + 1) * 4);
    int* cursor   = (int*)alloc((size_t)N_NODES * 4);
    int* csr_src  = (int*)alloc((size_t)E0 * 4);
    int* start    = (int*)alloc((N_GRAPHS + 1) * 4);
    int* bsum     = (int*)alloc(SCAN_B * 4);
    int* bpre     = (int*)alloc(SCAN_B * 4);
    float* AS     = (float*)alloc((size_t)N_NODES * 4);
    float* AD     = (float*)alloc((size_t)N_NODES * 4);
    float* wfold  = (float*)alloc(6 * 128 * 4);
    _Float16* H16 = (_Float16*)alloc((size_t)N_NODES * HID * 2);
    float* FA     = (float*)alloc((size_t)N_NODES * HID * 4);
    float* FB     = (float*)alloc((size_t)N_NODES * HID * 4);
    float* partial = (float*)alloc((size_t)N_GRAPHS * 16 * 128 * 4);
    _Float16* Wh[3], *Wl[3];
    for (int l = 0; l < 3; ++l) {
        Wh[l] = (_Float16*)alloc(16384 * 2);
        Wl[l] = (_Float16*)alloc(16384 * 2);
    }

    // CSR build + boundaries (sentinel init folded into count, find folded into scan)
    hipMemsetAsync(counts, 0, (size_t)N_NODES * 4, stream);
    count_kernel<<<(E0 + 255) / 256, 256, 0, stream>>>(edst, E0, counts, start);
    block_reduce<<<SCAN_B, 256, 0, stream>>>(counts, bsum);
    scan_bsum<<<1, 256, 0, stream>>>(bsum, bpre, offs);
    block_scan<<<SCAN_B, 256, 0, stream>>>(counts, bpre, batch, offs, cursor, start);
    scatter_kernel<<<(E0 + 255) / 256, 256, 0, stream>>>(esrc, edst, E0, cursor, csr_src);

    // fused weight prep
    pack_prep<<<30, 256, 0, stream>>>(W[0], W[1], W[2], avs[0], avd[0], avs[1], avd[1],
                                      avs[2], avd[2], Wh[0], Wl[0], Wh[1], Wl[1], Wh[2], Wl[2],
                                      wfold);

    // 3 GAT layers
    const float* cur = x;
    float* feat[2] = {FA, FB};
    for (int l = 0; l < 3; ++l) {
        gemm_mfma<<<(N_NODES + 63) / 64, 256, 0, stream>>>(cur, Wh[l], Wl[l],
                                                           wfold + (l * 2) * 128,
                                                           wfold + (l * 2 + 1) * 128,
                                                           H16, AS, AD);
        float* nxt = feat[l & 1];
        aggregate_kernel<<<(N_NODES + 3) / 4, 256, 0, stream>>>(H16, AS, AD, offs, csr_src,
                                                                bb[l], nxt);
        cur = nxt;
    }

    // global mean pool (2-phase)
    pool_partial<<<N_GRAPHS * 16, 128, 0, stream>>>(cur, start, partial);
    pool_final<<<N_GRAPHS, 128, 0, stream>>>(partial, start, (float*)d_out);
}

// Round 9
// 345.642 us; speedup vs baseline: 1.1254x; 1.0362x over previous
//
#include <hip/hip_runtime.h>
#include <math.h>

#define N_NODES 50000
#define N_GRAPHS 64
#define HID 128
#define SCAN_B 196  // ceil(50000/256)

typedef _Float16 half8 __attribute__((ext_vector_type(8)));
typedef float f32x4 __attribute__((ext_vector_type(4)));

__device__ __forceinline__ float lrelu(float e) { return e > 0.f ? e : 0.2f * e; }
// fast ELU: absolute error ~1e-7 (v_exp based), fine vs 1.3e-3 absmax threshold
__device__ __forceinline__ float elu_fast(float o) { return o > 0.f ? o : __expf(o) - 1.f; }

// ---------------- CSR build ----------------
__global__ void count_kernel(const int* __restrict__ dst, int n_e, int* __restrict__ counts,
                             int* __restrict__ start) {
    if (blockIdx.x == 0 && threadIdx.x <= N_GRAPHS) start[threadIdx.x] = -1;
    int e = blockIdx.x * blockDim.x + threadIdx.x;
    if (e < n_e) atomicAdd(&counts[dst[e]], 1);
}

__global__ __launch_bounds__(256) void block_reduce(const int* __restrict__ counts,
                                                    int* __restrict__ bsum) {
    __shared__ int red[256];
    int t = threadIdx.x;
    int i = blockIdx.x * 256 + t;
    red[t] = (i < N_NODES) ? counts[i] : 0;
    __syncthreads();
#pragma unroll
    for (int off = 128; off; off >>= 1) {
        if (t < off) red[t] += red[t + off];
        __syncthreads();
    }
    if (t == 0) bsum[blockIdx.x] = red[0];
}

__global__ __launch_bounds__(256) void scan_bsum(const int* __restrict__ bsum,
                                                 int* __restrict__ bpre,
                                                 int* __restrict__ offs) {
    __shared__ int sh[256];
    int t = threadIdx.x;
    int v = (t < SCAN_B) ? bsum[t] : 0;
    sh[t] = v;
    __syncthreads();
#pragma unroll
    for (int off = 1; off < 256; off <<= 1) {
        int u = (t >= off) ? sh[t - off] : 0;
        __syncthreads();
        sh[t] += u;
        __syncthreads();
    }
    if (t < SCAN_B) bpre[t] = sh[t] - v;
    if (t == SCAN_B - 1) offs[N_NODES] = sh[t];
}

__global__ __launch_bounds__(256) void block_scan(const int* __restrict__ counts,
                                                  const int* __restrict__ bpre,
                                                  const int* __restrict__ batch,
                                                  int* __restrict__ offs,
                                                  int* __restrict__ cursor,
                                                  int* __restrict__ start) {
    __shared__ int sh[256];
    int t = threadIdx.x;
    int i = blockIdx.x * 256 + t;
    int c = (i < N_NODES) ? counts[i] : 0;
    sh[t] = c;
    __syncthreads();
#pragma unroll
    for (int off = 1; off < 256; off <<= 1) {
        int u = (t >= off) ? sh[t - off] : 0;
        __syncthreads();
        sh[t] += u;
        __syncthreads();
    }
    if (i < N_NODES) {
        int e = bpre[blockIdx.x] + sh[t] - c;
        offs[i] = e;
        cursor[i] = e;
        int b = batch[i];
        if (i == 0) start[b] = 0;
        else if (batch[i - 1] != b) start[b] = i;
    }
}

__global__ void scatter_kernel(const int* __restrict__ src, const int* __restrict__ dst, int n_e,
                               int* __restrict__ cursor, int* __restrict__ csr_src) {
    int e = blockIdx.x * blockDim.x + threadIdx.x;
    if (e >= n_e) return;
    int d = dst[e];
    int pos = atomicAdd(&cursor[d], 1);
    csr_src[pos] = src[e];
}

// ---------------- fused weight prep: split-f16 fragment pack + alpha fold ----------------
__global__ __launch_bounds__(256) void pack_prep(const float* __restrict__ W0,
                                                 const float* __restrict__ W1,
                                                 const float* __restrict__ W2,
                                                 const float* __restrict__ as0,
                                                 const float* __restrict__ ad0,
                                                 const float* __restrict__ as1,
                                                 const float* __restrict__ ad1,
                                                 const float* __restrict__ as2,
                                                 const float* __restrict__ ad2,
                                                 _Float16* __restrict__ Wh0, _Float16* __restrict__ Wl0,
                                                 _Float16* __restrict__ Wh1, _Float16* __restrict__ Wl1,
                                                 _Float16* __restrict__ Wh2, _Float16* __restrict__ Wl2,
                                                 float* __restrict__ wfold) {
    int b = blockIdx.x;
    if (b < 24) {
        int layer = b >> 3;
        const float* W = layer == 0 ? W0 : (layer == 1 ? W1 : W2);
        _Float16* Wh = layer == 0 ? Wh0 : (layer == 1 ? Wh1 : Wh2);
        _Float16* Wl = layer == 0 ? Wl0 : (layer == 1 ? Wl1 : Wl2);
        int t = (b & 7) * 256 + threadIdx.x;
        int lane = t & 63;
        int nt = (t >> 6) & 7;
        int kt = t >> 9;
        int n = nt * 16 + (lane & 15);
        int kbase = kt * 32 + (lane >> 4) * 8;
#pragma unroll
        for (int j = 0; j < 8; ++j) {
            float w = W[(size_t)(kbase + j) * 128 + n];
            _Float16 h = (_Float16)w;
            float r = w - (float)h;
            size_t idx = (size_t)t * 8 + j;
            Wh[idx] = h;
            Wl[idx] = (_Float16)r;
        }
    } else {
        int idx = b - 24;  // 0..5: layer*2 + which
        int layer = idx >> 1, which = idx & 1;
        const float* W = layer == 0 ? W0 : (layer == 1 ? W1 : W2);
        const float* a = which == 0 ? (layer == 0 ? as0 : (layer == 1 ? as1 : as2))
                                    : (layer == 0 ? ad0 : (layer == 1 ? ad1 : ad2));
        int k = threadIdx.x;
        if (k < 128) {
            float s = 0.f;
            for (int j = 0; j < 128; ++j) s = fmaf(W[k * 128 + j], a[j], s);
            wfold[idx * 128 + k] = s;
        }
    }
}

// ---------------- MFMA GEMM: H16 = fp16(X)@W (2-term); exact fp32 alphas in-loop ----------------
__global__ __launch_bounds__(256) void gemm_mfma(const float* __restrict__ X,
                                                 const _Float16* __restrict__ Wh,
                                                 const _Float16* __restrict__ Wl,
                                                 const float* __restrict__ wsv,
                                                 const float* __restrict__ wdv,
                                                 _Float16* __restrict__ H16,
                                                 float* __restrict__ AS,
                                                 float* __restrict__ AD) {
    __shared__ float wsL[128], wdL[128];
    int t = threadIdx.x;
    if (t < 128) wsL[t] = wsv[t];
    else if (t < 256) wdL[t - 128] = wdv[t - 128];
    __syncthreads();

    int wave = t >> 6, lane = t & 63;
    int m15 = lane & 15, quad = lane >> 4;
    int rowbase = blockIdx.x * 64 + wave * 16;
    int arow = rowbase + m15;
    bool arow_ok = arow < N_NODES;

    f32x4 acc[8];
#pragma unroll
    for (int nt = 0; nt < 8; ++nt) acc[nt] = (f32x4){0.f, 0.f, 0.f, 0.f};
    float as_p = 0.f, ad_p = 0.f;

    const float* xrow = X + (size_t)arow * 128 + quad * 8;
#pragma unroll
    for (int kt = 0; kt < 4; ++kt) {
        f32x4 a0 = (f32x4){0.f, 0.f, 0.f, 0.f};
        f32x4 a1 = (f32x4){0.f, 0.f, 0.f, 0.f};
        if (arow_ok) {
            a0 = *(const f32x4*)(xrow + kt * 32);
            a1 = *(const f32x4*)(xrow + kt * 32 + 4);
        }
        int kb = kt * 32 + quad * 8;
        half8 ah;
#pragma unroll
        for (int j = 0; j < 4; ++j) {
            as_p = fmaf(a0[j], wsL[kb + j], as_p);
            ad_p = fmaf(a0[j], wdL[kb + j], ad_p);
            as_p = fmaf(a1[j], wsL[kb + 4 + j], as_p);
            ad_p = fmaf(a1[j], wdL[kb + 4 + j], ad_p);
            ah[j] = (_Float16)a0[j];
            ah[4 + j] = (_Float16)a1[j];
        }
#pragma unroll
        for (int nt = 0; nt < 8; ++nt) {
            size_t fidx = ((size_t)((kt * 8 + nt) * 64 + lane)) * 8;
            half8 bh = *(const half8*)(Wh + fidx);
            half8 bl = *(const half8*)(Wl + fidx);
            acc[nt] = __builtin_amdgcn_mfma_f32_16x16x32_f16(ah, bh, acc[nt], 0, 0, 0);
            acc[nt] = __builtin_amdgcn_mfma_f32_16x16x32_f16(ah, bl, acc[nt], 0, 0, 0);
        }
    }

#pragma unroll
    for (int nt = 0; nt < 8; ++nt) {
        int c = nt * 16 + m15;
#pragma unroll
        for (int reg = 0; reg < 4; ++reg) {
            int gr = rowbase + quad * 4 + reg;
            if (gr < N_NODES) H16[(size_t)gr * 128 + c] = (_Float16)acc[nt][reg];
        }
    }
    as_p += __shfl_xor(as_p, 16);
    ad_p += __shfl_xor(ad_p, 16);
    as_p += __shfl_xor(as_p, 32);
    ad_p += __shfl_xor(ad_p, 32);
    if (quad == 0 && arow_ok) { AS[arow] = as_p; AD[arow] = ad_p; }
}

// ---------------- fused softmax + fp16 gather: one wave per node ----------------
// Fast-math transcendentals (__expf, rcp) — absolute-error impact ~1e-7, threshold 1.3e-3.
// (src, coef) packed as int2 in LDS -> one ds_read_b64 broadcast per edge.
__global__ __launch_bounds__(256) void aggregate_kernel(const _Float16* __restrict__ H16,
                                                        const float* __restrict__ AS,
                                                        const float* __restrict__ AD,
                                                        const int* __restrict__ offs,
                                                        const int* __restrict__ csr_src,
                                                        const float* __restrict__ bias,
                                                        float* __restrict__ OUT) {
    __shared__ int2 sh_sp[4][64];
    int w = threadIdx.x >> 6, lane = threadIdx.x & 63;
    int node = blockIdx.x * 4 + w;
    bool valid = node < N_NODES;

    int beg = 0, deg = 0;
    float ad = 0.f, eself = 0.f;
    if (valid) {
        beg = offs[node];
        deg = offs[node + 1] - beg;
        ad = AD[node];
        eself = lrelu(AS[node] + ad);
    }
    bool fast = deg <= 64;
    float m = 0.f, inv = 1.f, ps = 0.f;

    if (valid) {
        if (fast) {
            int s = 0;
            float ev = -INFINITY;
            if (lane < deg) {
                s = csr_src[beg + lane];
                ev = lrelu(AS[s] + ad);
            }
            m = ev;
#pragma unroll
            for (int off = 32; off; off >>= 1) m = fmaxf(m, __shfl_xor(m, off));
            m = fmaxf(m, eself);
            float p = (lane < deg) ? __expf(ev - m) : 0.f;
            float ssum = p;
#pragma unroll
            for (int off = 32; off; off >>= 1) ssum += __shfl_xor(ssum, off);
            ps = __expf(eself - m);
            inv = __builtin_amdgcn_rcpf(ssum + ps + 1e-16f);
            ps *= inv;
            float pc = p * inv;
            sh_sp[w][lane] = make_int2(s, __float_as_int(pc));
        } else {
            float mym = -INFINITY;
            for (int i = beg + lane; i < beg + deg; i += 64)
                mym = fmaxf(mym, lrelu(AS[csr_src[i]] + ad));
#pragma unroll
            for (int off = 32; off; off >>= 1) mym = fmaxf(mym, __shfl_xor(mym, off));
            m = fmaxf(mym, eself);
            float ssum = 0.f;
            for (int i = beg + lane; i < beg + deg; i += 64)
                ssum += __expf(lrelu(AS[csr_src[i]] + ad) - m);
#pragma unroll
            for (int off = 32; off; off >>= 1) ssum += __shfl_xor(ssum, off);
            ps = __expf(eself - m);
            inv = __builtin_amdgcn_rcpf(ssum + ps + 1e-16f);
            ps *= inv;
        }
    }
    __syncthreads();

    int q = lane >> 4, l16 = lane & 15;
    const half8* H8 = (const half8*)H16;  // row = 16 half8
    float accA[8] = {0.f, 0.f, 0.f, 0.f, 0.f, 0.f, 0.f, 0.f};
    float accB[8] = {0.f, 0.f, 0.f, 0.f, 0.f, 0.f, 0.f, 0.f};

    if (valid) {
        if (fast) {
            int k = q;
            for (; k + 4 < deg; k += 8) {
                int2 sp0 = sh_sp[w][k];
                int2 sp1 = sh_sp[w][k + 4];
                float c0 = __int_as_float(sp0.y);
                float c1 = __int_as_float(sp1.y);
                half8 h0 = H8[(size_t)sp0.x * 16 + l16];
                half8 h1 = H8[(size_t)sp1.x * 16 + l16];
#pragma unroll
                for (int i = 0; i < 8; ++i) {
                    accA[i] = fmaf(c0, (float)h0[i], accA[i]);
                    accB[i] = fmaf(c1, (float)h1[i], accB[i]);
                }
            }
            if (k < deg) {
                int2 sp0 = sh_sp[w][k];
                float c0 = __int_as_float(sp0.y);
                half8 h0 = H8[(size_t)sp0.x * 16 + l16];
#pragma unroll
                for (int i = 0; i < 8; ++i) accA[i] = fmaf(c0, (float)h0[i], accA[i]);
            }
        } else {
            for (int k = q; k < deg; k += 4) {
                int s = csr_src[beg + k];
                float c = __expf(lrelu(AS[s] + ad) - m) * inv;
                half8 h0 = H8[(size_t)s * 16 + l16];
#pragma unroll
                for (int i = 0; i < 8; ++i) accA[i] = fmaf(c, (float)h0[i], accA[i]);
            }
        }
    }

#pragma unroll
    for (int i = 0; i < 8; ++i) {
        accA[i] += accB[i];
        accA[i] += __shfl_xor(accA[i], 16);
        accA[i] += __shfl_xor(accA[i], 32);
    }

    if (valid && q == 0) {
        half8 hs = H8[(size_t)node * 16 + l16];
        f32x4 b4a = ((const f32x4*)bias)[l16 * 2];
        f32x4 b4b = ((const f32x4*)bias)[l16 * 2 + 1];
        f32x4 o0, o1;
        o0.x = fmaf(ps, (float)hs[0], accA[0]) + b4a.x;
        o0.y = fmaf(ps, (float)hs[1], accA[1]) + b4a.y;
        o0.z = fmaf(ps, (float)hs[2], accA[2]) + b4a.z;
        o0.w = fmaf(ps, (float)hs[3], accA[3]) + b4a.w;
        o1.x = fmaf(ps, (float)hs[4], accA[4]) + b4b.x;
        o1.y = fmaf(ps, (float)hs[5], accA[5]) + b4b.y;
        o1.z = fmaf(ps, (float)hs[6], accA[6]) + b4b.z;
        o1.w = fmaf(ps, (float)hs[7], accA[7]) + b4b.w;
        o0.x = elu_fast(o0.x);
        o0.y = elu_fast(o0.y);
        o0.z = elu_fast(o0.z);
        o0.w = elu_fast(o0.w);
        o1.x = elu_fast(o1.x);
        o1.y = elu_fast(o1.y);
        o1.z = elu_fast(o1.z);
        o1.w = elu_fast(o1.w);
        ((f32x4*)OUT)[(size_t)node * 32 + l16 * 2] = o0;
        ((f32x4*)OUT)[(size_t)node * 32 + l16 * 2 + 1] = o1;
    }
}

// ---------------- global mean pool: 2-phase, sentinel-walking boundaries ----------------
__device__ __forceinline__ int estart(const int* __restrict__ start, int g) {
    for (; g < N_GRAPHS; ++g) {
        int v = start[g];
        if (v >= 0) return v;
    }
    return N_NODES;
}

__global__ __launch_bounds__(128) void pool_partial(const float* __restrict__ F,
                                                    const int* __restrict__ start,
                                                    float* __restrict__ partial) {
    int b = blockIdx.x;
    int g = b >> 4, sub = b & 15;
    int c = threadIdx.x;
    int s0 = estart(start, g), e0 = estart(start, g + 1);
    float acc = 0.f;
    for (int i = s0 + sub; i < e0; i += 16) acc += F[(size_t)i * 128 + c];
    partial[(size_t)b * 128 + c] = acc;
}

__global__ __launch_bounds__(128) void pool_final(const float* __restrict__ partial,
                                                  const int* __restrict__ start,
                                                  float* __restrict__ out) {
    int g = blockIdx.x;
    int c = threadIdx.x;
    float v = 0.f;
#pragma unroll
    for (int u = 0; u < 16; ++u) v += partial[(size_t)(g * 16 + u) * 128 + c];
    int cnt = estart(start, g + 1) - estart(start, g);
    out[(size_t)g * 128 + c] = v / (float)(cnt > 1 ? cnt : 1);
}

extern "C" void kernel_launch(void* const* d_in, const int* in_sizes, int n_in,
                              void* d_out, int out_size, void* d_ws, size_t ws_size,
                              hipStream_t stream) {
    const float* x = (const float*)d_in[0];
    const int* edge_index = (const int*)d_in[1];
    const int* batch = (const int*)d_in[2];
    const float* W[3]   = {(const float*)d_in[3], (const float*)d_in[7], (const float*)d_in[11]};
    const float* avs[3] = {(const float*)d_in[4], (const float*)d_in[8], (const float*)d_in[12]};
    const float* avd[3] = {(const float*)d_in[5], (const float*)d_in[9], (const float*)d_in[13]};
    const float* bb[3]  = {(const float*)d_in[6], (const float*)d_in[10], (const float*)d_in[14]};
    int E0 = in_sizes[1] / 2;
    const int* esrc = edge_index;
    const int* edst = edge_index + E0;

    char* p = (char*)d_ws;
    auto alloc = [&](size_t bytes) -> void* {
        void* q = (void*)p;
        p += (bytes + 255) & ~(size_t)255;
        return q;
    };
    int* counts   = (int*)alloc((size_t)N_NODES * 4);
    int* offs     = (int*)alloc((size_t)(N_NODES + 1) * 4);
    int* cursor   = (int*)alloc((size_t)N_NODES * 4);
    int* csr_src  = (int*)alloc((size_t)E0 * 4);
    int* start    = (int*)alloc((N_GRAPHS + 1) * 4);
    int* bsum     = (int*)alloc(SCAN_B * 4);
    int* bpre     = (int*)alloc(SCAN_B * 4);
    float* AS     = (float*)alloc((size_t)N_NODES * 4);
    float* AD     = (float*)alloc((size_t)N_NODES * 4);
    float* wfold  = (float*)alloc(6 * 128 * 4);
    _Float16* H16 = (_Float16*)alloc((size_t)N_NODES * HID * 2);
    float* FA     = (float*)alloc((size_t)N_NODES * HID * 4);
    float* FB     = (float*)alloc((size_t)N_NODES * HID * 4);
    float* partial = (float*)alloc((size_t)N_GRAPHS * 16 * 128 * 4);
    _Float16* Wh[3], *Wl[3];
    for (int l = 0; l < 3; ++l) {
        Wh[l] = (_Float16*)alloc(16384 * 2);
        Wl[l] = (_Float16*)alloc(16384 * 2);
    }

    // CSR build + boundaries
    hipMemsetAsync(counts, 0, (size_t)N_NODES * 4, stream);
    count_kernel<<<(E0 + 255) / 256, 256, 0, stream>>>(edst, E0, counts, start);
    block_reduce<<<SCAN_B, 256, 0, stream>>>(counts, bsum);
    scan_bsum<<<1, 256, 0, stream>>>(bsum, bpre, offs);
    block_scan<<<SCAN_B, 256, 0, stream>>>(counts, bpre, batch, offs, cursor, start);
    scatter_kernel<<<(E0 + 255) / 256, 256, 0, stream>>>(esrc, edst, E0, cursor, csr_src);

    // fused weight prep
    pack_prep<<<30, 256, 0, stream>>>(W[0], W[1], W[2], avs[0], avd[0], avs[1], avd[1],
                                      avs[2], avd[2], Wh[0], Wl[0], Wh[1], Wl[1], Wh[2], Wl[2],
                                      wfold);

    // 3 GAT layers
    const float* cur = x;
    float* feat[2] = {FA, FB};
    for (int l = 0; l < 3; ++l) {
        gemm_mfma<<<(N_NODES + 63) / 64, 256, 0, stream>>>(cur, Wh[l], Wl[l],
                                                           wfold + (l * 2) * 128,
                                                           wfold + (l * 2 + 1) * 128,
                                                           H16, AS, AD);
        float* nxt = feat[l & 1];
        aggregate_kernel<<<(N_NODES + 3) / 4, 256, 0, stream>>>(H16, AS, AD, offs, csr_src,
                                                                bb[l], nxt);
        cur = nxt;
    }

    // global mean pool (2-phase)
    pool_partial<<<N_GRAPHS * 16, 128, 0, stream>>>(cur, start, partial);
    pool_final<<<N_GRAPHS, 128, 0, stream>>>(partial, start, (float*)d_out);
}